// Round 10
// baseline (40.618 us; speedup 1.0000x reference)
//
#include <hip/hip_runtime.h>
#include <math.h>

// GBST forward. B=8, L=2048, D=256, NGRAM=4. R21 = R20 (best, 27.1us) with
// k_prep FUSED via device-scope flag handshake (single dispatch):
//  - blocks 0..63 (32768 thr) each convert one ushort2-pair of proj_w/ff_w
//    into the fragment-major bf16 workspace (exactly k_prep's mapping),
//    then t0 release-stores flag[blockIdx]=MAGIC (agent scope: flushes the
//    writer XCD L2). All blocks: tokens+ballot+conv FIRST (no weights
//    needed), then lane-parallel spin-acquire on the 64 flags, then issue
//    weight slabs. Prep + its latency hide under conv; the k_prep launch
//    and inter-kernel drain (~2-4us of the 27.1) vanish.
//  - Deadlock-free by arithmetic: 344 blocks < 512 resident slots
//    (53.8KB LDS -> 2 blocks/CU x 256 CUs), so prep blocks always run.
//  - Flags live in re-poisoned d_ws -> fresh handshake every iteration;
//    MAGIC != any plausible poison; wrong weights would fail absmax.
// Kept from R20: cvtpk packs, NT out stores, hoisted tokens, M=48/8-wave,
// 4-deep slab ping-pong, 3 barriers.

#define D_ 256
#define M_ 48                 // positions per block (3 stripes of 16; 12 | 48)
#define BPB 43                // ceil(2048/48)
#define LSTR 264              // ushort stride: 528B, 16B-aligned
#define MAGIC 0x1F2E3D4Cu

typedef __attribute__((ext_vector_type(8))) short bf16x8;
typedef __attribute__((ext_vector_type(4))) float f32x4;

__device__ __forceinline__ float bf2f(ushort h) {
    union { unsigned u; float f; } v; v.u = ((unsigned)h) << 16;
    return v.f;
}
// packed RNE f32x2 -> bf16x2 (lo = first arg); 1 VALU op
__device__ __forceinline__ unsigned cvtpk(float lo, float hi) {
    unsigned r;
    asm("v_cvt_pk_bf16_f32 %0, %1, %2" : "=v"(r) : "v"(lo), "v"(hi));
    return r;
}

// load one k8-slab (2 B-frags for this wave's n-pair), fragment-major
#define LDB2(v0, v1, W, K8) do { \
    const ushort* bp_ = (W) + ((size_t)((K8) * 16 + w * 2) * 64 + ln) * 8; \
    v0 = *(const bf16x8*)(bp_); \
    v1 = *(const bf16x8*)(bp_ + 512); \
} while (0)

// 6 MFMAs for one k8: 2 n-tiles x 3 m-stripes
#define MFMA6(ACC, K8, v0, v1) do { \
    bf16x8 a0_ = *(const bf16x8*)&x_lds[lr][(K8) * 32 + koff]; \
    bf16x8 a1_ = *(const bf16x8*)&x_lds[16 + lr][(K8) * 32 + koff]; \
    bf16x8 a2_ = *(const bf16x8*)&x_lds[32 + lr][(K8) * 32 + koff]; \
    ACC[0][0] = __builtin_amdgcn_mfma_f32_16x16x32_bf16(a0_, v0, ACC[0][0], 0, 0, 0); \
    ACC[1][0] = __builtin_amdgcn_mfma_f32_16x16x32_bf16(a1_, v0, ACC[1][0], 0, 0, 0); \
    ACC[2][0] = __builtin_amdgcn_mfma_f32_16x16x32_bf16(a2_, v0, ACC[2][0], 0, 0, 0); \
    ACC[0][1] = __builtin_amdgcn_mfma_f32_16x16x32_bf16(a0_, v1, ACC[0][1], 0, 0, 0); \
    ACC[1][1] = __builtin_amdgcn_mfma_f32_16x16x32_bf16(a1_, v1, ACC[1][1], 0, 0, 0); \
    ACC[2][1] = __builtin_amdgcn_mfma_f32_16x16x32_bf16(a2_, v1, ACC[2][1], 0, 0, 0); \
} while (0)

#define SBAR __builtin_amdgcn_sched_barrier(0)

// ---------------------------------------------------------------------------
// Single kernel: 512 threads / 8 waves, M=48, fused prep + flag handshake.
// ---------------------------------------------------------------------------
__global__ __launch_bounds__(512, 4) void k_main(
    const int* __restrict__ seq, const float* __restrict__ emb,
    const float* __restrict__ conv_w, const float* __restrict__ conv_b,
    const float* __restrict__ pw, const float* __restrict__ proj_b,
    const float* __restrict__ score_w,
    const float* __restrict__ fw, const float* __restrict__ ff_b,
    ushort* __restrict__ wqp, ushort* __restrict__ wqf,
    unsigned* __restrict__ flag,
    float* __restrict__ out, int L)
{
    __shared__ ushort x_lds[M_][LSTR];   // conv x (A proj) -> o (A FF)
    __shared__ ushort x2[M_][LSTR];      // masked x (mix input)
    __shared__ float xsred[8][M_];
    __shared__ float wts[8][12][4];      // per-wave copy; tile = w>>1
    const int b  = blockIdx.x / BPB;
    const int l0 = (blockIdx.x % BPB) * M_;
    const int t  = threadIdx.x;
    const int w  = t >> 6, ln = t & 63;
    const int lr = ln & 15, q = ln >> 4;
    const int koff = q * 8;
    const int g   = t >> 7;              // row-group 0..3 (wave-uniform)
    const int ch0 = (t & 127) * 2;       // channel pair (conv & mix)
    const int base = g * 12;             // conv row base

    // ---- fused prep slice: blocks 0..63 convert one ushort2-pair each ----
    const int gtid = blockIdx.x * 512 + t;
    if (gtid < 32768) {
        int i = gtid * 2;                // 0,2,..,65534
        int j  = i & 7;                  // even
        int lnp = (i >> 3) & 63;
        int nb = (i >> 9) & 15;
        int k8 = i >> 13;
        int er = nb * 16 + (lnp & 15);
        int k  = k8 * 32 + (lnp >> 4) * 8 + j;
        float2 p2 = *(const float2*)(pw + er * D_ + k);
        float2 f2 = *(const float2*)(fw + er * D_ + k);
        *(unsigned*)(wqp + i) = cvtpk(p2.x, p2.y);
        *(unsigned*)(wqf + i) = cvtpk(f2.x, f2.y);
    }
    if (blockIdx.x < 64) {
        __syncthreads();                 // all block's weight stores complete
        if (t == 0)
            __hip_atomic_store(&flag[blockIdx.x], MAGIC,
                               __ATOMIC_RELEASE, __HIP_MEMORY_SCOPE_AGENT);
    }

    const int* seqp = seq + (size_t)b * L + l0;

    // ---- hoisted token loads; OOB (l>=L) -> -1 (true zero rows);
    //      PAD tokens stay 0 (emb[0] IS fed to conv, per reference) ----
    int tokv[15];
    #pragma unroll
    for (int r = 0; r < 15; ++r)
        tokv[r] = (l0 + base + r < L) ? seqp[base + r] : -1;

    // ---- validity mask: one coalesced lane-load + ballot ----
    unsigned long long vmask;
    {
        int sv = (ln < M_ && l0 + ln < L) ? seqp[ln] : 0;
        vmask = __ballot(sv > 0);
    }

    // ---- conv: row-group g rows base..base+11, channel pair ch0;
    //      emb read f32, x16 (sqrt D) folded into taps; cvtpk pack ----
    {
        float4 wa = *(const float4*)(conv_w + ch0 * 4);
        float4 wb = *(const float4*)(conv_w + ch0 * 4 + 4);
        wa.x *= 16.f; wa.y *= 16.f; wa.z *= 16.f; wa.w *= 16.f;
        wb.x *= 16.f; wb.y *= 16.f; wb.z *= 16.f; wb.w *= 16.f;
        const float cba = conv_b[ch0], cbb = conv_b[ch0 + 1];
        float2 er[15];
        #pragma unroll
        for (int r = 0; r < 15; ++r) {
            int sn_ = __builtin_amdgcn_readfirstlane(tokv[r]);
            float2 e_; e_.x = 0.f; e_.y = 0.f;
            if (sn_ >= 0) e_ = *(const float2*)(emb + (size_t)sn_ * D_ + ch0);
            er[r] = e_;
        }
        #pragma unroll
        for (int r = 0; r < 12; ++r) {
            float cx = fmaf(wa.x, er[r].x, fmaf(wa.y, er[r+1].x,
                       fmaf(wa.z, er[r+2].x, fmaf(wa.w, er[r+3].x, cba))));
            float cy = fmaf(wb.x, er[r].y, fmaf(wb.y, er[r+1].y,
                       fmaf(wb.z, er[r+2].y, fmaf(wb.w, er[r+3].y, cbb))));
            *(unsigned*)&x_lds[base + r][ch0] = cvtpk(cx, cy);
        }
    }

    // ---- spin-acquire the 64 prep flags (lane ln checks flag[ln]) ----
    while (__hip_atomic_load(&flag[ln], __ATOMIC_ACQUIRE,
                             __HIP_MEMORY_SCOPE_AGENT) != MAGIC)
        __builtin_amdgcn_s_sleep(2);

    // slab registers (4-deep ping-pong, shared by proj and FF pipelines)
    bf16x8 s00, s01, s10, s11, s20, s21, s30, s31;
    LDB2(s00, s01, wqp, 0);
    LDB2(s10, s11, wqp, 1);
    LDB2(s20, s21, wqp, 2);
    LDB2(s30, s31, wqp, 3);
    SBAR;
    __syncthreads();   // B0: conv done -> A readable (all waves past spin)

    // ---- proj GEMM: 4-slab-deep pipeline, fully unrolled ----
    f32x4 acc[3][2];
    #pragma unroll
    for (int s = 0; s < 3; ++s)
        #pragma unroll
        for (int n = 0; n < 2; ++n) acc[s][n] = (f32x4){0.f, 0.f, 0.f, 0.f};
    MFMA6(acc, 0, s00, s01); LDB2(s00, s01, wqp, 4); SBAR;
    MFMA6(acc, 1, s10, s11); LDB2(s10, s11, wqp, 5); SBAR;
    MFMA6(acc, 2, s20, s21); LDB2(s20, s21, wqp, 6); SBAR;
    MFMA6(acc, 3, s30, s31); LDB2(s30, s31, wqp, 7); SBAR;
    MFMA6(acc, 4, s00, s01);
    MFMA6(acc, 5, s10, s11);
    MFMA6(acc, 6, s20, s21);
    MFMA6(acc, 7, s30, s31);

    // ---- epilogue: mask+bias -> x2 (cvtpk single) + score partials ----
    {
        float xsp[12];
        #pragma unroll
        for (int i = 0; i < 12; ++i) xsp[i] = 0.f;
        #pragma unroll
        for (int n = 0; n < 2; ++n) {
            int e = w * 32 + n * 16 + lr;
            float pb = proj_b[e], sw = score_w[e];
            #pragma unroll
            for (int s = 0; s < 3; ++s) {
                #pragma unroll
                for (int r = 0; r < 4; ++r) {
                    int row = s * 16 + q * 4 + r;
                    float v = ((vmask >> row) & 1ull) ? acc[s][n][r] + pb : 0.f;
                    x2[row][e] = (ushort)cvtpk(v, v);   // RNE, 1 VALU
                    xsp[s * 4 + r] = fmaf(v, sw, xsp[s * 4 + r]);
                }
            }
        }
        #pragma unroll
        for (int off = 1; off < 16; off <<= 1) {
            #pragma unroll
            for (int i = 0; i < 12; ++i) xsp[i] += __shfl_xor(xsp[i], off, 64);
        }
        if (lr == 0) {
            #pragma unroll
            for (int s = 0; s < 3; ++s)
                #pragma unroll
                for (int r = 0; r < 4; ++r)
                    xsred[w][s * 16 + q * 4 + r] = xsp[s * 4 + r];
        }
    }
    __syncthreads();   // B1: x2 + xsred complete; x_lds A-reads all done

    // issue FF slabs 0..3 NOW -> latency hides under wts+mix VALU work
    LDB2(s00, s01, wqf, 0);
    LDB2(s10, s11, wqf, 1);
    LDB2(s20, s21, wqf, 2);
    LDB2(s30, s31, wqf, 3);
    SBAR;

    // ---- softmax weights (per-wave redundant; lanes 0..11; tile = w>>1) ----
    if (ln < 12) {
        const int p = (w >> 1) * 12 + ln;   // global row
        // per-row total score (8-way cross-wave sum)
        float xt = xsred[0][p] + xsred[1][p] + xsred[2][p] + xsred[3][p]
                 + xsred[4][p] + xsred[5][p] + xsred[6][p] + xsred[7][p];
        // group-neighbor sums via shfl (BEFORE validity branch: sources active;
        // 12 | group bases so local index == in-tile index)
        int i2 = ln & ~1;
        float s2 = __shfl(xt, i2, 64) + __shfl(xt, i2 + 1, 64);
        int i3 = ln - (ln % 3);
        float s3 = __shfl(xt, i3, 64) + __shfl(xt, i3 + 1, 64)
                 + __shfl(xt, i3 + 2, 64);
        int i4 = ln & ~3;
        float s4 = __shfl(xt, i4, 64) + __shfl(xt, i4 + 1, 64)
                 + __shfl(xt, i4 + 2, 64) + __shfl(xt, i4 + 3, 64);
        if (!((vmask >> p) & 1ull)) {
            wts[w][ln][0] = wts[w][ln][1] = wts[w][ln][2] = wts[w][ln][3] = 0.f;
        } else {
            int r2 = p & ~1, r4 = p & ~3;
            int r3 = p - (p % 3);
            float c2 = (float)__popcll((vmask >> r2) & 3ull);    // >=1: p valid
            float c3 = (float)__popcll((vmask >> r3) & 7ull);
            float c4 = (float)__popcll((vmask >> r4) & 15ull);
            float m2 = s2 / c2, m3 = s3 / c3, m4 = s4 / c4;
            float mx = fmaxf(fmaxf(xt, m2), fmaxf(m3, m4));
            float q0 = __expf(xt - mx), q2 = __expf(m2 - mx);
            float q3 = __expf(m3 - mx), q4 = __expf(m4 - mx);
            float iZ = 1.f / (q0 + 2.f * q2 + 3.f * q3 + 4.f * q4);
            wts[w][ln][0] = q0 * iZ;
            wts[w][ln][1] = 2.f * q2 * iZ / c2;   // inv counts folded
            wts[w][ln][2] = 3.f * q3 * iZ / c3;
            wts[w][ln][3] = 4.f * q4 * iZ / c4;
        }
    }
    asm volatile("s_waitcnt lgkmcnt(0)" ::: "memory");
    SBAR;

    // ---- mix: tile g (= w>>1), channel pair ch0; cvtpk pack out ----
    {
        const int r0 = g * 12;
        float2 xr[12];
        #pragma unroll
        for (int p = 0; p < 12; ++p) {
            unsigned v = *(const unsigned*)&x2[r0 + p][ch0];
            xr[p].x = bf2f((ushort)(v & 0xffff));
            xr[p].y = bf2f((ushort)(v >> 16));
        }
        float s2x[6], s2y[6], s3x[4], s3y[4], s4x[3], s4y[3];
        #pragma unroll
        for (int j = 0; j < 6; ++j) {
            s2x[j] = xr[2*j].x + xr[2*j+1].x;
            s2y[j] = xr[2*j].y + xr[2*j+1].y;
        }
        #pragma unroll
        for (int j = 0; j < 4; ++j) {
            s3x[j] = xr[3*j].x + xr[3*j+1].x + xr[3*j+2].x;
            s3y[j] = xr[3*j].y + xr[3*j+1].y + xr[3*j+2].y;
        }
        #pragma unroll
        for (int j = 0; j < 3; ++j) {
            s4x[j] = xr[4*j].x + xr[4*j+1].x + xr[4*j+2].x + xr[4*j+3].x;
            s4y[j] = xr[4*j].y + xr[4*j+1].y + xr[4*j+2].y + xr[4*j+3].y;
        }
        #pragma unroll
        for (int p = 0; p < 12; ++p) {
            float4 wv = *(const float4*)&wts[w][p][0];
            float ox = wv.x*xr[p].x + wv.y*s2x[p>>1] + wv.z*s3x[p/3] + wv.w*s4x[p>>2];
            float oy = wv.x*xr[p].y + wv.y*s2y[p>>1] + wv.z*s3y[p/3] + wv.w*s4y[p>>2];
            *(unsigned*)&x_lds[r0 + p][ch0] = cvtpk(ox, oy);
        }
    }
    __syncthreads();   // B2: o rows done

    // ---- FF GEMM: 4-slab-deep pipeline (slabs 0..3 already in flight) ----
    f32x4 ffa[3][2];
    #pragma unroll
    for (int s = 0; s < 3; ++s)
        #pragma unroll
        for (int n = 0; n < 2; ++n) ffa[s][n] = (f32x4){0.f, 0.f, 0.f, 0.f};
    MFMA6(ffa, 0, s00, s01); LDB2(s00, s01, wqf, 4); SBAR;
    MFMA6(ffa, 1, s10, s11); LDB2(s10, s11, wqf, 5); SBAR;
    MFMA6(ffa, 2, s20, s21); LDB2(s20, s21, wqf, 6); SBAR;
    MFMA6(ffa, 3, s30, s31); LDB2(s30, s31, wqf, 7); SBAR;
    MFMA6(ffa, 4, s00, s01);
    MFMA6(ffa, 5, s10, s11);
    MFMA6(ffa, 6, s20, s21);
    MFMA6(ffa, 7, s30, s31);

    // ---- store out = o + relu(ff + fb), l < L; NT: don't pollute L2 ----
    #pragma unroll
    for (int n = 0; n < 2; ++n) {
        int e = w * 32 + n * 16 + lr;
        float fb = ff_b[e];
        #pragma unroll
        for (int s = 0; s < 3; ++s) {
            #pragma unroll
            for (int r = 0; r < 4; ++r) {
                int row = s * 16 + q * 4 + r;
                int l = l0 + row;
                if (l < L) {
                    float o = bf2f(x_lds[row][e]);
                    __builtin_nontemporal_store(
                        o + fmaxf(ffa[s][n][r] + fb, 0.f),
                        &out[((size_t)b * L + l) * D_ + e]);
                }
            }
        }
    }
}

// ---------------------------------------------------------------------------
extern "C" void kernel_launch(void* const* d_in, const int* in_sizes, int n_in,
                              void* d_out, int out_size, void* d_ws, size_t ws_size,
                              hipStream_t stream) {
    const int*   seq     = (const int*)d_in[0];
    // d_in[1] = group_id : redundant (groups are pos//s, validity = seq!=0)
    const float* emb     = (const float*)d_in[2];
    const float* conv_w  = (const float*)d_in[3];
    const float* conv_b  = (const float*)d_in[4];
    const float* proj_w  = (const float*)d_in[5];
    const float* proj_b  = (const float*)d_in[6];
    const float* score_w = (const float*)d_in[7];
    // d_in[8] = score_b : constant shift, cancels in softmax
    const float* ff_w    = (const float*)d_in[9];
    const float* ff_b    = (const float*)d_in[10];
    float* out = (float*)d_out;

    const int L = 2048;
    const int B = in_sizes[0] / L;

    ushort* wqp = (ushort*)d_ws;          // [65536] bf16 fragment-major
    ushort* wqf = wqp + D_ * D_;          // [65536] bf16 fragment-major
    unsigned* flag = (unsigned*)(wqf + D_ * D_);   // [64] handshake flags

    k_main<<<B * BPB, 512, 0, stream>>>(seq, emb, conv_w, conv_b, proj_w,
                                        proj_b, score_w, ff_w, ff_b,
                                        wqp, wqf, flag, out, L);
}

// Round 11
// 27.071 us; speedup vs baseline: 1.5004x; 1.5004x over previous
//
#include <hip/hip_runtime.h>
#include <math.h>

// GBST forward. B=8, L=2048, D=256, NGRAM=4. R22 = R20 revert (best, 27.1us)
// + float4 k_prep (only delta).
// R21 post-mortem: fused prep via agent-scope flag handshake cost ~20us --
// the RELEASE store emits an L2 writeback per prep block (64 flushes) and
// 2752 waves spin-polling 4 cache lines serialize. Kernel-boundary
// producer->consumer is CHEAPER than in-grid handshake at this size.
// Ledger: structural levers all flat (MFMA -25% R13, L2 -50% R13, code
// size 4x R15, prefetch depth R18, occupancy 2<->4 blk/CU R19, fusion
// R14/R21); wins were VALU cuts (cvtpk -0.65) + NT stores/token hoist
// (-0.8). k_main measured idle on all pipes -> short-dispatch low-clock +
// latency floor ~23us; prep+launch ~4us. This round: halve k_prep's
// instruction/wavefront count (float4/ushort4, 64 blocks).

#define D_ 256
#define M_ 48                 // positions per block (3 stripes of 16; 12 | 48)
#define BPB 43                // ceil(2048/48)
#define LSTR 264              // ushort stride: 528B, 16B-aligned

typedef __attribute__((ext_vector_type(8))) short bf16x8;
typedef __attribute__((ext_vector_type(4))) float f32x4;

__device__ __forceinline__ float bf2f(ushort h) {
    union { unsigned u; float f; } v; v.u = ((unsigned)h) << 16;
    return v.f;
}
// packed RNE f32x2 -> bf16x2 (lo = first arg); 1 VALU op
__device__ __forceinline__ unsigned cvtpk(float lo, float hi) {
    unsigned r;
    asm("v_cvt_pk_bf16_f32 %0, %1, %2" : "=v"(r) : "v"(lo), "v"(hi));
    return r;
}

// load one k8-slab (2 B-frags for this wave's n-pair), fragment-major
#define LDB2(v0, v1, W, K8) do { \
    const ushort* bp_ = (W) + ((size_t)((K8) * 16 + w * 2) * 64 + ln) * 8; \
    v0 = *(const bf16x8*)(bp_); \
    v1 = *(const bf16x8*)(bp_ + 512); \
} while (0)

// 6 MFMAs for one k8: 2 n-tiles x 3 m-stripes
#define MFMA6(ACC, K8, v0, v1) do { \
    bf16x8 a0_ = *(const bf16x8*)&x_lds[lr][(K8) * 32 + koff]; \
    bf16x8 a1_ = *(const bf16x8*)&x_lds[16 + lr][(K8) * 32 + koff]; \
    bf16x8 a2_ = *(const bf16x8*)&x_lds[32 + lr][(K8) * 32 + koff]; \
    ACC[0][0] = __builtin_amdgcn_mfma_f32_16x16x32_bf16(a0_, v0, ACC[0][0], 0, 0, 0); \
    ACC[1][0] = __builtin_amdgcn_mfma_f32_16x16x32_bf16(a1_, v0, ACC[1][0], 0, 0, 0); \
    ACC[2][0] = __builtin_amdgcn_mfma_f32_16x16x32_bf16(a2_, v0, ACC[2][0], 0, 0, 0); \
    ACC[0][1] = __builtin_amdgcn_mfma_f32_16x16x32_bf16(a0_, v1, ACC[0][1], 0, 0, 0); \
    ACC[1][1] = __builtin_amdgcn_mfma_f32_16x16x32_bf16(a1_, v1, ACC[1][1], 0, 0, 0); \
    ACC[2][1] = __builtin_amdgcn_mfma_f32_16x16x32_bf16(a2_, v1, ACC[2][1], 0, 0, 0); \
} while (0)

#define SBAR __builtin_amdgcn_sched_barrier(0)

// ---------------------------------------------------------------------------
// K0: proj_w/ff_w -> bf16 FRAGMENT-MAJOR, 4 elements/thread (one j-quad):
// wq[((k8*16+nb)*64+ln)*8+j] = w[(nb*16+(ln&15))*256 + k8*32+(ln>>4)*8+j]
// ---------------------------------------------------------------------------
__global__ __launch_bounds__(256) void k_prep(
    const float* __restrict__ pw, const float* __restrict__ fw,
    ushort* __restrict__ wqp, ushort* __restrict__ wqf)
{
    int i = (blockIdx.x * 256 + threadIdx.x) * 4;   // 0,4,..,65532
    int j  = i & 7;                                  // 0 or 4
    int ln = (i >> 3) & 63;
    int nb = (i >> 9) & 15;
    int k8 = i >> 13;
    int er = nb * 16 + (ln & 15);
    int k  = k8 * 32 + (ln >> 4) * 8 + j;
    float4 p4 = *(const float4*)(pw + er * D_ + k);
    float4 f4 = *(const float4*)(fw + er * D_ + k);
    uint2 po; po.x = cvtpk(p4.x, p4.y); po.y = cvtpk(p4.z, p4.w);
    uint2 fo; fo.x = cvtpk(f4.x, f4.y); fo.y = cvtpk(f4.z, f4.w);
    *(uint2*)(wqp + i) = po;
    *(uint2*)(wqf + i) = fo;
}

// ---------------------------------------------------------------------------
// K1: 512 threads / 8 waves, M=48 positions, 3 barriers, 4-deep GEMM pipes.
// ---------------------------------------------------------------------------
__global__ __launch_bounds__(512, 4) void k_main(
    const int* __restrict__ seq, const float* __restrict__ emb,
    const float* __restrict__ conv_w, const float* __restrict__ conv_b,
    const ushort* __restrict__ wqp, const float* __restrict__ proj_b,
    const float* __restrict__ score_w,
    const ushort* __restrict__ wqf, const float* __restrict__ ff_b,
    float* __restrict__ out, int L)
{
    __shared__ ushort x_lds[M_][LSTR];   // conv x (A proj) -> o (A FF)
    __shared__ ushort x2[M_][LSTR];      // masked x (mix input)
    __shared__ float xsred[8][M_];
    __shared__ float wts[8][12][4];      // per-wave copy; tile = w>>1
    const int b  = blockIdx.x / BPB;
    const int l0 = (blockIdx.x % BPB) * M_;
    const int t  = threadIdx.x;
    const int w  = t >> 6, ln = t & 63;
    const int lr = ln & 15, q = ln >> 4;
    const int koff = q * 8;
    const int g   = t >> 7;              // row-group 0..3 (wave-uniform)
    const int ch0 = (t & 127) * 2;       // channel pair (conv & mix)
    const int base = g * 12;             // conv row base

    const int* seqp = seq + (size_t)b * L + l0;

    // ---- hoisted token loads; OOB (l>=L) -> -1 (true zero rows);
    //      PAD tokens stay 0 (emb[0] IS fed to conv, per reference) ----
    int tokv[15];
    #pragma unroll
    for (int r = 0; r < 15; ++r)
        tokv[r] = (l0 + base + r < L) ? seqp[base + r] : -1;

    // ---- validity mask: one coalesced lane-load + ballot ----
    unsigned long long vmask;
    {
        int sv = (ln < M_ && l0 + ln < L) ? seqp[ln] : 0;
        vmask = __ballot(sv > 0);
    }

    // slab registers (4-deep ping-pong, shared by proj and FF pipelines)
    bf16x8 s00, s01, s10, s11, s20, s21, s30, s31;
    LDB2(s00, s01, wqp, 0);
    LDB2(s10, s11, wqp, 1);
    LDB2(s20, s21, wqp, 2);
    LDB2(s30, s31, wqp, 3);
    SBAR;

    // ---- conv: row-group g rows base..base+11, channel pair ch0;
    //      emb read f32, x16 (sqrt D) folded into taps; cvtpk pack ----
    {
        float4 wa = *(const float4*)(conv_w + ch0 * 4);
        float4 wb = *(const float4*)(conv_w + ch0 * 4 + 4);
        wa.x *= 16.f; wa.y *= 16.f; wa.z *= 16.f; wa.w *= 16.f;
        wb.x *= 16.f; wb.y *= 16.f; wb.z *= 16.f; wb.w *= 16.f;
        const float cba = conv_b[ch0], cbb = conv_b[ch0 + 1];
        float2 er[15];
        #pragma unroll
        for (int r = 0; r < 15; ++r) {
            int sn_ = __builtin_amdgcn_readfirstlane(tokv[r]);
            float2 e_; e_.x = 0.f; e_.y = 0.f;
            if (sn_ >= 0) e_ = *(const float2*)(emb + (size_t)sn_ * D_ + ch0);
            er[r] = e_;
        }
        #pragma unroll
        for (int r = 0; r < 12; ++r) {
            float cx = fmaf(wa.x, er[r].x, fmaf(wa.y, er[r+1].x,
                       fmaf(wa.z, er[r+2].x, fmaf(wa.w, er[r+3].x, cba))));
            float cy = fmaf(wb.x, er[r].y, fmaf(wb.y, er[r+1].y,
                       fmaf(wb.z, er[r+2].y, fmaf(wb.w, er[r+3].y, cbb))));
            *(unsigned*)&x_lds[base + r][ch0] = cvtpk(cx, cy);
        }
    }
    __syncthreads();   // B0: conv done -> A readable

    // ---- proj GEMM: 4-slab-deep pipeline, fully unrolled ----
    f32x4 acc[3][2];
    #pragma unroll
    for (int s = 0; s < 3; ++s)
        #pragma unroll
        for (int n = 0; n < 2; ++n) acc[s][n] = (f32x4){0.f, 0.f, 0.f, 0.f};
    MFMA6(acc, 0, s00, s01); LDB2(s00, s01, wqp, 4); SBAR;
    MFMA6(acc, 1, s10, s11); LDB2(s10, s11, wqp, 5); SBAR;
    MFMA6(acc, 2, s20, s21); LDB2(s20, s21, wqp, 6); SBAR;
    MFMA6(acc, 3, s30, s31); LDB2(s30, s31, wqp, 7); SBAR;
    MFMA6(acc, 4, s00, s01);
    MFMA6(acc, 5, s10, s11);
    MFMA6(acc, 6, s20, s21);
    MFMA6(acc, 7, s30, s31);

    // ---- epilogue: mask+bias -> x2 (cvtpk single) + score partials ----
    {
        float xsp[12];
        #pragma unroll
        for (int i = 0; i < 12; ++i) xsp[i] = 0.f;
        #pragma unroll
        for (int n = 0; n < 2; ++n) {
            int e = w * 32 + n * 16 + lr;
            float pb = proj_b[e], sw = score_w[e];
            #pragma unroll
            for (int s = 0; s < 3; ++s) {
                #pragma unroll
                for (int r = 0; r < 4; ++r) {
                    int row = s * 16 + q * 4 + r;
                    float v = ((vmask >> row) & 1ull) ? acc[s][n][r] + pb : 0.f;
                    x2[row][e] = (ushort)cvtpk(v, v);   // RNE, 1 VALU
                    xsp[s * 4 + r] = fmaf(v, sw, xsp[s * 4 + r]);
                }
            }
        }
        #pragma unroll
        for (int off = 1; off < 16; off <<= 1) {
            #pragma unroll
            for (int i = 0; i < 12; ++i) xsp[i] += __shfl_xor(xsp[i], off, 64);
        }
        if (lr == 0) {
            #pragma unroll
            for (int s = 0; s < 3; ++s)
                #pragma unroll
                for (int r = 0; r < 4; ++r)
                    xsred[w][s * 16 + q * 4 + r] = xsp[s * 4 + r];
        }
    }
    __syncthreads();   // B1: x2 + xsred complete; x_lds A-reads all done

    // issue FF slabs 0..3 NOW -> latency hides under wts+mix VALU work
    LDB2(s00, s01, wqf, 0);
    LDB2(s10, s11, wqf, 1);
    LDB2(s20, s21, wqf, 2);
    LDB2(s30, s31, wqf, 3);
    SBAR;

    // ---- softmax weights (per-wave redundant; lanes 0..11; tile = w>>1) ----
    if (ln < 12) {
        const int p = (w >> 1) * 12 + ln;   // global row
        // per-row total score (8-way cross-wave sum)
        float xt = xsred[0][p] + xsred[1][p] + xsred[2][p] + xsred[3][p]
                 + xsred[4][p] + xsred[5][p] + xsred[6][p] + xsred[7][p];
        // group-neighbor sums via shfl (BEFORE validity branch: sources active;
        // 12 | group bases so local index == in-tile index)
        int i2 = ln & ~1;
        float s2 = __shfl(xt, i2, 64) + __shfl(xt, i2 + 1, 64);
        int i3 = ln - (ln % 3);
        float s3 = __shfl(xt, i3, 64) + __shfl(xt, i3 + 1, 64)
                 + __shfl(xt, i3 + 2, 64);
        int i4 = ln & ~3;
        float s4 = __shfl(xt, i4, 64) + __shfl(xt, i4 + 1, 64)
                 + __shfl(xt, i4 + 2, 64) + __shfl(xt, i4 + 3, 64);
        if (!((vmask >> p) & 1ull)) {
            wts[w][ln][0] = wts[w][ln][1] = wts[w][ln][2] = wts[w][ln][3] = 0.f;
        } else {
            int r2 = p & ~1, r4 = p & ~3;
            int r3 = p - (p % 3);
            float c2 = (float)__popcll((vmask >> r2) & 3ull);    // >=1: p valid
            float c3 = (float)__popcll((vmask >> r3) & 7ull);
            float c4 = (float)__popcll((vmask >> r4) & 15ull);
            float m2 = s2 / c2, m3 = s3 / c3, m4 = s4 / c4;
            float mx = fmaxf(fmaxf(xt, m2), fmaxf(m3, m4));
            float q0 = __expf(xt - mx), q2 = __expf(m2 - mx);
            float q3 = __expf(m3 - mx), q4 = __expf(m4 - mx);
            float iZ = 1.f / (q0 + 2.f * q2 + 3.f * q3 + 4.f * q4);
            wts[w][ln][0] = q0 * iZ;
            wts[w][ln][1] = 2.f * q2 * iZ / c2;   // inv counts folded
            wts[w][ln][2] = 3.f * q3 * iZ / c3;
            wts[w][ln][3] = 4.f * q4 * iZ / c4;
        }
    }
    asm volatile("s_waitcnt lgkmcnt(0)" ::: "memory");
    SBAR;

    // ---- mix: tile g (= w>>1), channel pair ch0; cvtpk pack out ----
    {
        const int r0 = g * 12;
        float2 xr[12];
        #pragma unroll
        for (int p = 0; p < 12; ++p) {
            unsigned v = *(const unsigned*)&x2[r0 + p][ch0];
            xr[p].x = bf2f((ushort)(v & 0xffff));
            xr[p].y = bf2f((ushort)(v >> 16));
        }
        float s2x[6], s2y[6], s3x[4], s3y[4], s4x[3], s4y[3];
        #pragma unroll
        for (int j = 0; j < 6; ++j) {
            s2x[j] = xr[2*j].x + xr[2*j+1].x;
            s2y[j] = xr[2*j].y + xr[2*j+1].y;
        }
        #pragma unroll
        for (int j = 0; j < 4; ++j) {
            s3x[j] = xr[3*j].x + xr[3*j+1].x + xr[3*j+2].x;
            s3y[j] = xr[3*j].y + xr[3*j+1].y + xr[3*j+2].y;
        }
        #pragma unroll
        for (int j = 0; j < 3; ++j) {
            s4x[j] = xr[4*j].x + xr[4*j+1].x + xr[4*j+2].x + xr[4*j+3].x;
            s4y[j] = xr[4*j].y + xr[4*j+1].y + xr[4*j+2].y + xr[4*j+3].y;
        }
        #pragma unroll
        for (int p = 0; p < 12; ++p) {
            float4 wv = *(const float4*)&wts[w][p][0];
            float ox = wv.x*xr[p].x + wv.y*s2x[p>>1] + wv.z*s3x[p/3] + wv.w*s4x[p>>2];
            float oy = wv.x*xr[p].y + wv.y*s2y[p>>1] + wv.z*s3y[p/3] + wv.w*s4y[p>>2];
            *(unsigned*)&x_lds[r0 + p][ch0] = cvtpk(ox, oy);
        }
    }
    __syncthreads();   // B2: o rows done

    // ---- FF GEMM: 4-slab-deep pipeline (slabs 0..3 already in flight) ----
    f32x4 ffa[3][2];
    #pragma unroll
    for (int s = 0; s < 3; ++s)
        #pragma unroll
        for (int n = 0; n < 2; ++n) ffa[s][n] = (f32x4){0.f, 0.f, 0.f, 0.f};
    MFMA6(ffa, 0, s00, s01); LDB2(s00, s01, wqf, 4); SBAR;
    MFMA6(ffa, 1, s10, s11); LDB2(s10, s11, wqf, 5); SBAR;
    MFMA6(ffa, 2, s20, s21); LDB2(s20, s21, wqf, 6); SBAR;
    MFMA6(ffa, 3, s30, s31); LDB2(s30, s31, wqf, 7); SBAR;
    MFMA6(ffa, 4, s00, s01);
    MFMA6(ffa, 5, s10, s11);
    MFMA6(ffa, 6, s20, s21);
    MFMA6(ffa, 7, s30, s31);

    // ---- store out = o + relu(ff + fb), l < L; NT: don't pollute L2 ----
    #pragma unroll
    for (int n = 0; n < 2; ++n) {
        int e = w * 32 + n * 16 + lr;
        float fb = ff_b[e];
        #pragma unroll
        for (int s = 0; s < 3; ++s) {
            #pragma unroll
            for (int r = 0; r < 4; ++r) {
                int row = s * 16 + q * 4 + r;
                int l = l0 + row;
                if (l < L) {
                    float o = bf2f(x_lds[row][e]);
                    __builtin_nontemporal_store(
                        o + fmaxf(ffa[s][n][r] + fb, 0.f),
                        &out[((size_t)b * L + l) * D_ + e]);
                }
            }
        }
    }
}

// ---------------------------------------------------------------------------
extern "C" void kernel_launch(void* const* d_in, const int* in_sizes, int n_in,
                              void* d_out, int out_size, void* d_ws, size_t ws_size,
                              hipStream_t stream) {
    const int*   seq     = (const int*)d_in[0];
    // d_in[1] = group_id : redundant (groups are pos//s, validity = seq!=0)
    const float* emb     = (const float*)d_in[2];
    const float* conv_w  = (const float*)d_in[3];
    const float* conv_b  = (const float*)d_in[4];
    const float* proj_w  = (const float*)d_in[5];
    const float* proj_b  = (const float*)d_in[6];
    const float* score_w = (const float*)d_in[7];
    // d_in[8] = score_b : constant shift, cancels in softmax
    const float* ff_w    = (const float*)d_in[9];
    const float* ff_b    = (const float*)d_in[10];
    float* out = (float*)d_out;

    const int L = 2048;
    const int B = in_sizes[0] / L;

    ushort* wqp = (ushort*)d_ws;          // [65536] bf16 fragment-major
    ushort* wqf = wqp + D_ * D_;          // [65536] bf16 fragment-major

    k_prep<<<D_ * D_ / 1024, 256, 0, stream>>>(proj_w, ff_w, wqp, wqf);
    k_main<<<B * BPB, 512, 0, stream>>>(seq, emb, conv_w, conv_b, wqp, proj_b,
                                        score_w, wqf, ff_b, out, L);
}